// Round 7
// baseline (34.345 us; speedup 1.0000x reference)
//
#include <hip/hip_runtime.h>
#include <math.h>

#define HALF_PI   1.57079632679489662f
#define INV_SQRT2 0.70710678118654752f
#define BT    256
#define GBF   2048                 // fused grid: 8 blocks/CU x 256 CU (full machine)
#define NTHF  (GBF * BT)           // 524288 threads; E <= 2*NTHF = 1048576
#define NPART 1024                 // fallback edge-kernel blocks

// ---------------------------------------------------------------------------
// Grid barrier, fence-based (no per-poll acquire -> no L2-invalidate storm).
//   bar[i*16]   i=0..63 : leaf counters (64B apart; 32 arrivals each)
//   bar[1024]           : super counter (64 leaf-promotions)
//   bar[1040]           : done flag (single line all blocks poll, RELAXED)
// Exactly one release fence (L2 writeback) before arrival and one acquire
// fence (L2 invalidate) after the flag — the cross-XCD handoff cost is paid
// once per barrier instead of once per poll iteration (R6's 350us bug).
// Relaxed RMW chains preserve fence-fence synchronization (C++ fence rules).
// ---------------------------------------------------------------------------
__device__ __forceinline__ void gridbar(int* bar) {
    __syncthreads();
    __builtin_amdgcn_fence(__ATOMIC_RELEASE, "agent");   // writeback dirty L2 once
    if (threadIdx.x == 0) {
        int v = __hip_atomic_fetch_add(&bar[(blockIdx.x & 63) * 16], 1,
                                       __ATOMIC_RELAXED, __HIP_MEMORY_SCOPE_AGENT);
        if (v == (GBF / 64) - 1) {                        // last arrival of this leaf
            int s = __hip_atomic_fetch_add(&bar[1024], 1,
                                           __ATOMIC_RELAXED, __HIP_MEMORY_SCOPE_AGENT);
            if (s == 63)
                __hip_atomic_store(&bar[1040], 1,
                                   __ATOMIC_RELAXED, __HIP_MEMORY_SCOPE_AGENT);
        }
        while (__hip_atomic_load(&bar[1040],
                                 __ATOMIC_RELAXED, __HIP_MEMORY_SCOPE_AGENT) == 0)
            __builtin_amdgcn_s_sleep(8);
    }
    __syncthreads();
    __builtin_amdgcn_fence(__ATOMIC_ACQUIRE, "agent");   // invalidate stale L1/L2 once
}

// 4-qubit real circuit for one edge: returns exp(attn/4)
__device__ __forceinline__ float edge_ex(float4 qv, float4 kv,
                                         const float* scz, const float* scx) {
    float qa[4] = {qv.x, qv.y, qv.z, qv.w};
    float ka[4] = {kv.x, kv.y, kv.z, kv.w};
    float u[4][2];
    #pragma unroll
    for (int w = 0; w < 4; ++w) {
        float s, c;
        __sincosf(qa[w] * 0.5f, &s, &c);
        u[w][0] = (c + s) * INV_SQRT2;
        u[w][1] = (c - s) * INV_SQRT2;
    }
    float a[16];
    #pragma unroll
    for (int x = 0; x < 16; ++x)
        a[x] = u[0][(x >> 3) & 1] * u[1][(x >> 2) & 1] *
               u[2][(x >> 1) & 1] * u[3][x & 1];
    #pragma unroll
    for (int w = 0; w < 4; ++w) {
        float si, co;
        __sincosf(ka[w] * 0.5f, &si, &co);
        const int cb = 1 << (3 - w);
        const int tb = 1 << (3 - ((w + 1) & 3));
        #pragma unroll
        for (int x = 0; x < 16; ++x) {
            if ((x & cb) && !(x & tb)) {
                float a0 = a[x], a1 = a[x | tb];
                a[x]      = co * a0 - si * a1;
                a[x | tb] = si * a0 + co * a1;
            }
        }
    }
    float attn = 0.f;
    #pragma unroll
    for (int q = 0; q < 4; ++q) {
        const int bit = 1 << (3 - q);
        float sz = 0.f, sx = 0.f;
        #pragma unroll
        for (int x = 0; x < 16; ++x) {
            float pp = a[x] * a[x];
            sz += (x & bit) ? -pp : pp;
            if (!(x & bit)) sx += a[x] * a[x | bit];
        }
        attn += scz[q] * sz - scx[q] * (2.f * sx);
    }
    return __expf(attn * 0.25f);
}

// ---------------------------------------------------------------------------
// Fused kernel; grid MUST be exactly GBF blocks. __launch_bounds__(BT,8)
// forces VGPR<=64 (measured 32 in R6) -> 8 blocks/CU -> all 2048 co-resident.
// ---------------------------------------------------------------------------
__global__ __launch_bounds__(BT, 8) void fused_qattn(
        const float* __restrict__ feat, const int* __restrict__ ei,
        const float* __restrict__ Wq, const float* __restrict__ bq,
        const float* __restrict__ Wk, const float* __restrict__ bk,
        const float* __restrict__ qp,
        int* barA, int* barB, float* partial, float* qtab, float* ktab,
        float* __restrict__ out, int N, int E)
{
    __shared__ float scz[4], scx[4];
    __shared__ float red[BT];
    const int tid  = threadIdx.x;
    const int gtid = blockIdx.x * BT + tid;

    if (tid < 4) {
        float phi = qp[3 * tid + 0];
        float th  = qp[3 * tid + 1];
        float sth, cth;
        sincosf(th, &sth, &cth);
        scz[tid] = cth;
        scx[tid] = sth * cosf(phi);
    }

    // ---------------- Phase A: node projections (8192 waves) ----------------
    {
        const int lane = tid & 63;
        const int wid  = gtid >> 6;
        const int nwid = NTHF >> 6;   // 8192

        float4 wq4[4], wk4[4];
        #pragma unroll
        for (int q = 0; q < 4; ++q) {
            wq4[q] = reinterpret_cast<const float4*>(Wq + q * 256)[lane];
            wk4[q] = reinterpret_cast<const float4*>(Wk + q * 256)[lane];
        }
        const int   g    = lane >> 3;
        const float bias = (g < 4) ? bq[g] : bk[g & 3];
        const bool hi  = (lane & 32) != 0;
        const bool s16 = (lane & 16) != 0;
        const bool s8  = (lane & 8)  != 0;

        for (int n = wid; n < N; n += nwid) {
            float4 f = reinterpret_cast<const float4*>(feat)[(size_t)n * 64 + lane];
            float acc[8];
            #pragma unroll
            for (int q = 0; q < 4; ++q) {
                acc[q]     = f.x * wq4[q].x + f.y * wq4[q].y + f.z * wq4[q].z + f.w * wq4[q].w;
                acc[4 + q] = f.x * wk4[q].x + f.y * wk4[q].y + f.z * wk4[q].z + f.w * wk4[q].w;
            }
            // multi-value butterfly: 10 shuffles per node
            #pragma unroll
            for (int j = 0; j < 4; ++j) {
                float give = hi ? acc[j] : acc[j + 4];
                float r = __shfl_xor(give, 32, 64);
                acc[j]     += hi ? 0.f : r;
                acc[j + 4] += hi ? r : 0.f;
            }
            #pragma unroll
            for (int j = 0; j < 2; ++j) {
                float giveLow  = hi ? acc[6 + j] : acc[2 + j];
                float giveHigh = hi ? acc[4 + j] : acc[j];
                float give = s16 ? giveHigh : giveLow;
                float r = __shfl_xor(give, 16, 64);
                acc[j]     += (!hi && !s16) ? r : 0.f;
                acc[2 + j] += (!hi &&  s16) ? r : 0.f;
                acc[4 + j] += ( hi && !s16) ? r : 0.f;
                acc[6 + j] += ( hi &&  s16) ? r : 0.f;
            }
            float a_even = hi ? (s16 ? acc[6] : acc[4]) : (s16 ? acc[2] : acc[0]);
            float a_odd  = hi ? (s16 ? acc[7] : acc[5]) : (s16 ? acc[3] : acc[1]);
            float give3 = s8 ? a_even : a_odd;
            float r3 = __shfl_xor(give3, 8, 64);
            float v = (s8 ? a_odd : a_even) + r3;
            v += __shfl_xor(v, 4, 64);
            v += __shfl_xor(v, 2, 64);
            v += __shfl_xor(v, 1, 64);

            if ((lane & 7) == 0) {
                float t = tanhf(v + bias) * HALF_PI;
                if (g < 4) qtab[(size_t)n * 4 + g] = t;
                else       ktab[(size_t)n * 4 + (g & 3)] = t;
            }
        }
    }

    gridbar(barA);

    // ---------------- Phase B: per-edge circuit (1 edge/thread/round) -------
    const float4* qtab4 = reinterpret_cast<const float4*>(qtab);
    const float4* ktab4 = reinterpret_cast<const float4*>(ktab);

    float ex[2];
    float lsum = 0.f;
    #pragma unroll
    for (int it = 0; it < 2; ++it) {
        const int e = gtid + it * NTHF;
        ex[it] = 0.f;
        if (e < E) {
            const int s = ei[e];
            const int d = ei[E + e];
            float v = edge_ex(qtab4[s], ktab4[d], scz, scx);
            ex[it] = v;
            lsum += v;
        }
    }

    red[tid] = lsum;
    __syncthreads();
    #pragma unroll
    for (int s = 128; s > 0; s >>= 1) {
        if (tid < s) red[tid] += red[tid + s];
        __syncthreads();
    }
    if (tid == 0) partial[blockIdx.x] = red[0];

    gridbar(barB);

    // ---------------- Phase C: redundant deterministic reduce + write -------
    float ps = 0.f;
    #pragma unroll
    for (int k = 0; k < GBF / BT; ++k) ps += partial[tid + k * BT];
    red[tid] = ps;
    __syncthreads();
    #pragma unroll
    for (int s = 128; s > 0; s >>= 1) {
        if (tid < s) red[tid] += red[tid + s];
        __syncthreads();
    }
    const float inv = 1.f / red[0];

    #pragma unroll
    for (int it = 0; it < 2; ++it) {
        const int e = gtid + it * NTHF;
        if (e < E) out[e] = ex[it] * inv;
    }
}

// ======================= Fallback: proven 3-kernel path =====================
__global__ __launch_bounds__(256) void node_qk(
        const float* __restrict__ feat,
        const float* __restrict__ Wq, const float* __restrict__ bq,
        const float* __restrict__ Wk, const float* __restrict__ bk,
        float* __restrict__ qtab, float* __restrict__ ktab, int N) {
    const int lane  = threadIdx.x & 63;
    const int wid   = (int)((blockIdx.x * blockDim.x + threadIdx.x) >> 6);
    const int nwid  = (int)((gridDim.x * blockDim.x) >> 6);
    float4 wq4[4], wk4[4];
    #pragma unroll
    for (int q = 0; q < 4; ++q) {
        wq4[q] = reinterpret_cast<const float4*>(Wq + q * 256)[lane];
        wk4[q] = reinterpret_cast<const float4*>(Wk + q * 256)[lane];
    }
    const int  g    = lane >> 3;
    const float bias = (g < 4) ? bq[g] : bk[g & 3];
    const bool hi  = (lane & 32) != 0;
    const bool s16 = (lane & 16) != 0;
    const bool s8  = (lane & 8)  != 0;
    for (int n = wid; n < N; n += nwid) {
        float4 f = reinterpret_cast<const float4*>(feat)[(size_t)n * 64 + lane];
        float acc[8];
        #pragma unroll
        for (int q = 0; q < 4; ++q) {
            acc[q]     = f.x * wq4[q].x + f.y * wq4[q].y + f.z * wq4[q].z + f.w * wq4[q].w;
            acc[4 + q] = f.x * wk4[q].x + f.y * wk4[q].y + f.z * wk4[q].z + f.w * wk4[q].w;
        }
        #pragma unroll
        for (int j = 0; j < 4; ++j) {
            float give = hi ? acc[j] : acc[j + 4];
            float r = __shfl_xor(give, 32, 64);
            acc[j]     += hi ? 0.f : r;
            acc[j + 4] += hi ? r : 0.f;
        }
        #pragma unroll
        for (int j = 0; j < 2; ++j) {
            float giveLow  = hi ? acc[6 + j] : acc[2 + j];
            float giveHigh = hi ? acc[4 + j] : acc[j];
            float give = s16 ? giveHigh : giveLow;
            float r = __shfl_xor(give, 16, 64);
            acc[j]     += (!hi && !s16) ? r : 0.f;
            acc[2 + j] += (!hi &&  s16) ? r : 0.f;
            acc[4 + j] += ( hi && !s16) ? r : 0.f;
            acc[6 + j] += ( hi &&  s16) ? r : 0.f;
        }
        float a_even = hi ? (s16 ? acc[6] : acc[4]) : (s16 ? acc[2] : acc[0]);
        float a_odd  = hi ? (s16 ? acc[7] : acc[5]) : (s16 ? acc[3] : acc[1]);
        float give3 = s8 ? a_even : a_odd;
        float r3 = __shfl_xor(give3, 8, 64);
        float v = (s8 ? a_odd : a_even) + r3;
        v += __shfl_xor(v, 4, 64);
        v += __shfl_xor(v, 2, 64);
        v += __shfl_xor(v, 1, 64);
        if ((lane & 7) == 0) {
            float t = tanhf(v + bias) * HALF_PI;
            if (g < 4) qtab[(size_t)n * 4 + g] = t;
            else       ktab[(size_t)n * 4 + (g & 3)] = t;
        }
    }
}

__global__ __launch_bounds__(256) void edge_attn(
        const int* __restrict__ ei,
        const float4* __restrict__ qtab, const float4* __restrict__ ktab,
        const float* __restrict__ qp,
        float* __restrict__ out, float* __restrict__ partial, int E) {
    __shared__ float scz[4], scx[4];
    __shared__ float red[256];
    const int tid = threadIdx.x;
    if (tid < 4) {
        float phi = qp[3 * tid + 0];
        float th  = qp[3 * tid + 1];
        float sth, cth;
        sincosf(th, &sth, &cth);
        scz[tid] = cth;
        scx[tid] = sth * cosf(phi);
    }
    __syncthreads();
    const int total = NPART * 256;
    float lsum = 0.f;
    #pragma unroll
    for (int i = 0; i < 4; ++i) {
        const int e = blockIdx.x * 256 + tid + i * total;
        if (e < E) {
            float v = edge_ex(qtab[ei[e]], ktab[ei[E + e]], scz, scx);
            out[e] = v;
            lsum += v;
        }
    }
    red[tid] = lsum;
    __syncthreads();
    #pragma unroll
    for (int s = 128; s > 0; s >>= 1) {
        if (tid < s) red[tid] += red[tid + s];
        __syncthreads();
    }
    if (tid == 0) partial[blockIdx.x] = red[0];
}

__global__ __launch_bounds__(256) void normalize_out(
        float* __restrict__ out, const float* __restrict__ partial, int E) {
    __shared__ float red[256];
    const int tid = threadIdx.x;
    float s = 0.f;
    #pragma unroll
    for (int k = 0; k < NPART / 256; ++k) s += partial[tid + k * 256];
    red[tid] = s;
    __syncthreads();
    #pragma unroll
    for (int st = 128; st > 0; st >>= 1) {
        if (tid < st) red[tid] += red[tid + st];
        __syncthreads();
    }
    const float inv = 1.f / red[0];
    const int total = (int)(gridDim.x * 256);
    for (int e = blockIdx.x * 256 + tid; e < E; e += total)
        out[e] *= inv;
}

extern "C" void kernel_launch(void* const* d_in, const int* in_sizes, int n_in,
                              void* d_out, int out_size, void* d_ws, size_t ws_size,
                              hipStream_t stream) {
    const float* feat = (const float*)d_in[0];
    const int*   ei   = (const int*)d_in[1];
    const float* Wq   = (const float*)d_in[2];
    const float* bq   = (const float*)d_in[3];
    const float* Wk   = (const float*)d_in[4];
    const float* bk   = (const float*)d_in[5];
    const float* qp   = (const float*)d_in[6];

    int D = in_sizes[2] / 4;          // 256
    int N = in_sizes[0] / D;          // 50000
    int E = in_sizes[1] / 2;          // 800000
    (void)D;

    // ws layout
    int*   barA    = (int*)d_ws;                 // 2048 ints (8 KB)
    int*   barB    = barA + 2048;                // 2048 ints (8 KB)
    float* partial = (float*)d_ws + 4096;        // 2048 floats (8 KB)
    float* qtab    = (float*)d_ws + 6144;        // 4N floats (16B aligned)
    float* ktab    = qtab + (size_t)N * 4;
    float* out     = (float*)d_out;

    // capture-time occupancy check (pure driver query; graph-capture-safe)
    int maxB = 0;
    hipError_t oerr = hipOccupancyMaxActiveBlocksPerMultiprocessor(
        &maxB, reinterpret_cast<const void*>(&fused_qattn), BT, 0);
    const bool fused_ok = (oerr == hipSuccess) && (maxB >= 8) &&
                          (E <= 2 * NTHF);

    if (fused_ok) {
        hipMemsetAsync(d_ws, 0, 16384, stream);  // zero both barrier arrays
        fused_qattn<<<GBF, BT, 0, stream>>>(feat, ei, Wq, bq, Wk, bk, qp,
                                            barA, barB, partial, qtab, ktab,
                                            out, N, E);
    } else {
        node_qk<<<2048, 256, 0, stream>>>(feat, Wq, bq, Wk, bk, qtab, ktab, N);
        edge_attn<<<NPART, 256, 0, stream>>>(ei, (const float4*)qtab,
                                             (const float4*)ktab, qp, out, partial, E);
        normalize_out<<<1024, 256, 0, stream>>>(out, partial, E);
    }
}